// Round 11
// baseline (344.240 us; speedup 1.0000x reference)
//
#include <hip/hip_runtime.h>
#include <hip/hip_bf16.h>
#include <stdint.h>

#define N_NODES 50000
#define N_EDGES 800000
#define NREL    8
#define NBASES  30
#define DIM     128
#define NSLOT   9                           // 8 relations + root
#define NCAT    (NSLOT*DIM)                 // 1152
#define SCAN_NB ((N_NODES + 255) / 256)     // 196 scan blocks (dst-only buckets)

typedef __attribute__((ext_vector_type(8))) short short8;
typedef __attribute__((ext_vector_type(4))) float floatx4;
typedef __hip_bfloat16  bf16;
typedef __hip_bfloat162 bf16x2;

__device__ inline ushort f2bu(float f) { bf16 b = __float2bfloat16(f); return *(ushort*)&b; }
__device__ inline float  bu2f(ushort u) { union { unsigned i; float f; } c; c.i = ((unsigned)u) << 16; return c.f; }

// ---------------- weight prep: WcatT[n][k], n = r*128+o (slot 8 = root); wrelT/wrootT[o][k] ----------------
__global__ void prep_weights(const float* __restrict__ basis, const float* __restrict__ comp,
                             const float* __restrict__ root, const float* __restrict__ w_rel,
                             const float* __restrict__ w_root,
                             bf16* __restrict__ WcatT, bf16* __restrict__ wrelT, bf16* __restrict__ wrootT) {
    int idx = blockIdx.x * blockDim.x + threadIdx.x;
    const int n_cat = NCAT * DIM;            // 147456
    const int n_sq  = DIM * DIM;             // 16384
    if (idx < n_cat) {
        int k = idx & 127, n = idx >> 7;
        int r = n >> 7, o = n & 127;
        float v;
        if (r < NREL) {
            v = 0.f;
            for (int b = 0; b < NBASES; ++b)
                v += comp[r * NBASES + b] * basis[(b * DIM + k) * DIM + o];
        } else {
            v = root[k * DIM + o];
        }
        WcatT[n * DIM + k] = __float2bfloat16(v);
    } else if (idx < n_cat + n_sq) {
        int t = idx - n_cat; int k = t & 127, o = t >> 7;
        wrelT[o * DIM + k] = __float2bfloat16(w_rel[k * DIM + o]);
    } else if (idx < n_cat + 2 * n_sq) {
        int t = idx - n_cat - n_sq; int k = t & 127, o = t >> 7;
        wrootT[o * DIM + k] = __float2bfloat16(w_root[k * DIM + o]);
    }
}

// ---------------- fp32 -> bf16 node features (vectorized x4) ----------------
__global__ void conv_x(const float4* __restrict__ x4, ushort4* __restrict__ xb4, int n4) {
    int i = blockIdx.x * blockDim.x + threadIdx.x;
    if (i < n4) {
        float4 f = x4[i];
        ushort4 o;
        o.x = f2bu(f.x); o.y = f2bu(f.y); o.z = f2bu(f.z); o.w = f2bu(f.w);
        xb4[i] = o;
    }
}

// ---------------- counting sort by dst (50k buckets) ----------------
__global__ void hist_kernel(const int* __restrict__ ei, int* __restrict__ deg) {
    int e = blockIdx.x * blockDim.x + threadIdx.x;
    if (e < N_EDGES) atomicAdd(&deg[ei[N_EDGES + e]], 1);
}

__global__ void scan_blocks(const int* __restrict__ deg, int* __restrict__ segoff,
                            int* __restrict__ bsum, int n) {
    __shared__ int buf[256];
    int tid = threadIdx.x;
    int i = blockIdx.x * 256 + tid;
    int v = (i < n) ? deg[i] : 0;
    buf[tid] = v;
    __syncthreads();
#pragma unroll
    for (int o = 1; o < 256; o <<= 1) {
        int t = (tid >= o) ? buf[tid - o] : 0;
        __syncthreads();
        buf[tid] += t;
        __syncthreads();
    }
    if (i < n) segoff[i + 1] = buf[tid];
    if (tid == 255) bsum[blockIdx.x] = buf[255];
}

// single WAVE shuffle-scan of block sums -> exclusive (no barriers)
__global__ void scan_sums(int* __restrict__ bsum, int nb) {
    int lane = threadIdx.x;   // 64 threads
    int base = 0;
    for (int start = 0; start < nb; start += 64) {
        int i = start + lane;
        int v = (i < nb) ? bsum[i] : 0;
        int incl = v;
#pragma unroll
        for (int o = 1; o < 64; o <<= 1) {
            int t = __shfl_up(incl, o, 64);
            if (lane >= o) incl += t;
        }
        if (i < nb) bsum[i] = base + incl - v;   // exclusive
        base += __shfl(incl, 63, 64);
    }
}

__global__ void scan_add(int* __restrict__ segoff, const int* __restrict__ bsum, int n) {
    int i = blockIdx.x * 256 + threadIdx.x;
    if (i < n) segoff[i + 1] += bsum[blockIdx.x];
    if (i == 0) segoff[0] = 0;
}

// rec.x = src | (type<<16)   (src < 65536 guaranteed: N_NODES = 50000)
__global__ void scatter_kernel(const int* __restrict__ ei, const int* __restrict__ et,
                               const float* __restrict__ en, const int* __restrict__ segoff,
                               int* __restrict__ cur, uint2* __restrict__ rec) {
    int e = blockIdx.x * blockDim.x + threadIdx.x;
    if (e < N_EDGES) {
        int d = ei[N_EDGES + e];
        int p = segoff[d] + atomicAdd(&cur[d], 1);
        rec[p] = make_uint2((unsigned)ei[e] | ((unsigned)et[e] << 16), __float_as_uint(en[e]));
    }
}

// ---------------- MFMA GEMM (row-panel): proj[M,1152] = xb[M,128] @ WcatT[1152,128]^T ----------------
// Block stages its 64x128 A-panel ONCE, then loops the 18 B-tiles (wcat stays L2-resident).
// Epilogue per tile: fragments -> Bs (dead after MFMA), then full-line short8 stores (8x fewer
// store instructions than scalar fragment stores; R10 showed gemm1 store-instruction-bound).
__global__ __launch_bounds__(256) void gemm1_kernel(const bf16* __restrict__ A, const bf16* __restrict__ BT,
                                                    bf16* __restrict__ C, int M) {
    __shared__ ushort As[64][136];
    __shared__ ushort Bs[64][136];
    const ushort* Au = (const ushort*)A;
    const ushort* Bu = (const ushort*)BT;
    ushort* Cu = (ushort*)C;
    int tm = blockIdx.x * 64;
    int wave = threadIdx.x >> 6, lane = threadIdx.x & 63;
    int q = lane >> 4, mr = lane & 15;

    // stage A-panel once: 1024 short8 segs, 4/thread
#pragma unroll
    for (int u = 0; u < 4; ++u) {
        int cc = threadIdx.x + u * 256;
        int row = cc >> 4, seg = cc & 15;
        int gr = tm + row;
        short8 av = {0, 0, 0, 0, 0, 0, 0, 0};
        if (gr < M) av = *(const short8*)(Au + (size_t)gr * 128 + seg * 8);
        *(short8*)(&As[row][seg * 8]) = av;
    }

    floatx4 zero = {0.f, 0.f, 0.f, 0.f};
    for (int t = 0; t < 18; ++t) {
        if (t) __syncthreads();          // prior epilogue reads of Bs complete
        // stage B-tile (rows t*64..t*64+63 of WcatT): 1024 short8 segs, 4/thread
#pragma unroll
        for (int u = 0; u < 4; ++u) {
            int cc = threadIdx.x + u * 256;
            int row = cc >> 4, seg = cc & 15;
            short8 bv = *(const short8*)(Bu + (size_t)(t * 64 + row) * 128 + seg * 8);
            *(short8*)(&Bs[row][seg * 8]) = bv;
        }
        __syncthreads();
        floatx4 acc[4] = {zero, zero, zero, zero};
#pragma unroll
        for (int kt = 0; kt < 4; ++kt) {
            short8 a = *(const short8*)(&As[wave * 16 + mr][q * 8 + kt * 32]);
#pragma unroll
            for (int nt = 0; nt < 4; ++nt) {
                short8 b = *(const short8*)(&Bs[nt * 16 + mr][q * 8 + kt * 32]);
                acc[nt] = __builtin_amdgcn_mfma_f32_16x16x32_bf16(a, b, acc[nt], 0, 0, 0);
            }
        }
        // epilogue: fragments -> Bs (dead now), then cooperative full-line stores
        __syncthreads();
#pragma unroll
        for (int nt = 0; nt < 4; ++nt)
#pragma unroll
            for (int r4 = 0; r4 < 4; ++r4)
                Bs[wave * 16 + q * 4 + r4][nt * 16 + mr] = f2bu(acc[nt][r4]);
        __syncthreads();
        // 512 short8 segs, 2/thread; 8 lanes = one 128 B row-slice (full line)
#pragma unroll
        for (int u = 0; u < 2; ++u) {
            int cc = threadIdx.x + u * 256;
            int row = cc >> 3, seg = cc & 7;
            int gr = tm + row;
            if (gr < M) {
                short8 v = *(const short8*)(&Bs[row][seg * 8]);
                *(short8*)(Cu + (size_t)gr * NCAT + t * 64 + seg * 8) = v;
            }
        }
    }
}

// ---------------- layer-1 gather: quarter-wave (16 lanes/node, 16 B/lane), ILP-4 ----------------
// h[node] = sum_e norm_e * proj[src_e, type_e] + proj[node, root-slot] + bias1
__global__ void seg1_kernel(const uint2* __restrict__ rec, const int* __restrict__ segoff,
                            const ushort* __restrict__ proj, const float* __restrict__ bias1,
                            ushort* __restrict__ h) {
    int quad = threadIdx.x >> 4;
    int node = blockIdx.x * 16 + quad;
    if (node >= N_NODES) return;
    int lane = threadIdx.x & 15;
    int s = segoff[node], e = segoff[node + 1];
    float acc[8] = {0.f, 0.f, 0.f, 0.f, 0.f, 0.f, 0.f, 0.f};
    for (int chunk = s; chunk < e; chunk += 4) {
        int m = e - chunk; if (m > 4) m = 4;
        uint2 rr[4]; short8 vv[4];
#pragma unroll
        for (int j = 0; j < 4; ++j) if (j < m) rr[j] = rec[chunk + j];
#pragma unroll
        for (int j = 0; j < 4; ++j) if (j < m) {
            unsigned src = rr[j].x & 0xFFFFu;
            unsigned typ = rr[j].x >> 16;
            vv[j] = *(const short8*)(proj + ((size_t)src * NSLOT + typ) * 128 + lane * 8);
        }
#pragma unroll
        for (int j = 0; j < 4; ++j) if (j < m) {
            float norm = __uint_as_float(rr[j].y);
#pragma unroll
            for (int f = 0; f < 8; ++f) acc[f] += norm * bu2f((ushort)vv[j][f]);
        }
    }
    short8 base = *(const short8*)(proj + ((size_t)node * NSLOT + 8) * 128 + lane * 8);
    short8 o;
#pragma unroll
    for (int f = 0; f < 8; ++f)
        o[f] = (short)f2bu(acc[f] + bu2f((ushort)base[f]) + bias1[lane * 8 + f]);
    *(short8*)(h + (size_t)node * 128 + lane * 8) = o;
}

// ---------------- layer-2 segment sum: quarter-wave, ILP-4 ----------------
__global__ void seg2_kernel(const uint2* __restrict__ rec, const int* __restrict__ segoff,
                            const ushort* __restrict__ h, ushort* __restrict__ out2) {
    int quad = threadIdx.x >> 4;
    int node = blockIdx.x * 16 + quad;
    if (node >= N_NODES) return;
    int lane = threadIdx.x & 15;
    int s = segoff[node], e = segoff[node + 1];
    float acc[8] = {0.f, 0.f, 0.f, 0.f, 0.f, 0.f, 0.f, 0.f};
    for (int chunk = s; chunk < e; chunk += 4) {
        int m = e - chunk; if (m > 4) m = 4;
        uint2 rr[4]; short8 vv[4];
#pragma unroll
        for (int j = 0; j < 4; ++j) if (j < m) rr[j] = rec[chunk + j];
#pragma unroll
        for (int j = 0; j < 4; ++j) if (j < m)
            vv[j] = *(const short8*)(h + (size_t)(rr[j].x & 0xFFFFu) * 128 + lane * 8);
#pragma unroll
        for (int j = 0; j < 4; ++j) if (j < m)
#pragma unroll
            for (int f = 0; f < 8; ++f) acc[f] += bu2f((ushort)vv[j][f]);
    }
    short8 o;
#pragma unroll
    for (int f = 0; f < 8; ++f) o[f] = (short)f2bu(acc[f]);
    *(short8*)(out2 + (size_t)node * 128 + lane * 8) = o;
}

// ---------------- final GEMM: out[M,128](f32) = agg2nd@w_rel + h@w_root + b_rel ----------------
// Epilogue: stage f32 C-tile in LDS (reuse As as float[64][68]), then float4 full-line stores.
__global__ __launch_bounds__(256) void gemm2_kernel(const bf16* __restrict__ A1, const bf16* __restrict__ B1T,
                                                    const bf16* __restrict__ A2, const bf16* __restrict__ B2T,
                                                    const float* __restrict__ brel, float* __restrict__ out, int M) {
    __shared__ ushort As[64][136];
    __shared__ ushort Bs[64][136];
    int tm = blockIdx.x * 64, tn = blockIdx.y * 64;
    int wave = threadIdx.x >> 6, lane = threadIdx.x & 63;
    int q = lane >> 4, mr = lane & 15;
    floatx4 zero = {0.f, 0.f, 0.f, 0.f};
    floatx4 acc[4] = {zero, zero, zero, zero};

    for (int phase = 0; phase < 2; ++phase) {
        const ushort* Au = (const ushort*)(phase ? A2 : A1);
        const ushort* Bu = (const ushort*)(phase ? B2T : B1T);
        if (phase) __syncthreads();
        for (int c = threadIdx.x; c < 64 * 16; c += 256) {
            int row = c >> 4, seg = c & 15;
            int gr = tm + row;
            short8 av = {0, 0, 0, 0, 0, 0, 0, 0};
            if (gr < M) av = *(const short8*)(Au + (size_t)gr * 128 + seg * 8);
            *(short8*)(&As[row][seg * 8]) = av;
            short8 bv = *(const short8*)(Bu + (size_t)(tn + row) * 128 + seg * 8);
            *(short8*)(&Bs[row][seg * 8]) = bv;
        }
        __syncthreads();
#pragma unroll
        for (int kt = 0; kt < 4; ++kt) {
            short8 a = *(const short8*)(&As[wave * 16 + mr][q * 8 + kt * 32]);
#pragma unroll
            for (int nt = 0; nt < 4; ++nt) {
                short8 b = *(const short8*)(&Bs[nt * 16 + mr][q * 8 + kt * 32]);
                acc[nt] = __builtin_amdgcn_mfma_f32_16x16x32_bf16(a, b, acc[nt], 0, 0, 0);
            }
        }
    }
    // ---- epilogue: fragment (+bias) -> LDS floats (stride 68 = 272 B, fills As exactly) ----
    __syncthreads();
    float* Csf = (float*)&As[0][0];
#pragma unroll
    for (int nt = 0; nt < 4; ++nt)
#pragma unroll
        for (int r4 = 0; r4 < 4; ++r4) {
            int row = wave * 16 + q * 4 + r4;
            int col = nt * 16 + mr;
            Csf[row * 68 + col] = acc[nt][r4] + brel[tn + col];
        }
    __syncthreads();
    // cooperative float4 full-line stores: 1024 segs, 4/thread; 16 lanes = one 256 B row-slice
#pragma unroll
    for (int u = 0; u < 4; ++u) {
        int cc = threadIdx.x + u * 256;
        int row = cc >> 4, seg = cc & 15;
        int gr = tm + row;
        if (gr < M) {
            float4 v = *(const float4*)(&Csf[row * 68 + seg * 4]);
            *(float4*)(out + (size_t)gr * 128 + tn + seg * 4) = v;
        }
    }
}

extern "C" void kernel_launch(void* const* d_in, const int* in_sizes, int n_in,
                              void* d_out, int out_size, void* d_ws, size_t ws_size,
                              hipStream_t stream) {
    const float* x      = (const float*)d_in[0];
    const int*   ei     = (const int*)d_in[1];
    const int*   et     = (const int*)d_in[2];
    const float* en     = (const float*)d_in[3];
    const float* basis  = (const float*)d_in[4];
    const float* comp   = (const float*)d_in[5];
    const float* root   = (const float*)d_in[6];
    const float* bias1  = (const float*)d_in[7];
    const float* w_rel  = (const float*)d_in[8];
    const float* b_rel  = (const float*)d_in[9];
    const float* w_root = (const float*)d_in[10];
    float* out = (float*)d_out;

    char* ws = (char*)d_ws;
    size_t off = 0;
    auto alloc = [&](size_t bytes) { size_t o = off; off += (bytes + 255) & ~(size_t)255; return o; };

    size_t o_deg    = alloc((size_t)N_NODES * 4);        // zeroed
    size_t o_cur    = alloc((size_t)N_NODES * 4);        // zeroed (contiguous with deg)
    size_t o_segoff = alloc((size_t)(N_NODES + 1) * 4);
    size_t o_bsum   = alloc((size_t)SCAN_NB * 4);
    size_t o_rec    = alloc((size_t)N_EDGES * 8);
    size_t o_wcat   = alloc((size_t)NCAT * DIM * 2);
    size_t o_wrel   = alloc((size_t)DIM * DIM * 2);
    size_t o_wroot  = alloc((size_t)DIM * DIM * 2);
    size_t o_xb     = alloc((size_t)N_NODES * DIM * 2);
    size_t o_proj   = alloc((size_t)N_NODES * NCAT * 2); // 115.2 MB
    size_t o_hb     = alloc((size_t)N_NODES * DIM * 2);
    size_t o_agg2   = alloc((size_t)N_NODES * DIM * 2);

    int*   deg    = (int*)(ws + o_deg);
    int*   cur    = (int*)(ws + o_cur);
    int*   segoff = (int*)(ws + o_segoff);
    int*   bsum   = (int*)(ws + o_bsum);
    uint2* rec    = (uint2*)(ws + o_rec);
    bf16*  wcat   = (bf16*)(ws + o_wcat);
    bf16*  wrelT  = (bf16*)(ws + o_wrel);
    bf16*  wrootT = (bf16*)(ws + o_wroot);
    bf16*  xb     = (bf16*)(ws + o_xb);
    bf16*  proj   = (bf16*)(ws + o_proj);
    bf16*  hb     = (bf16*)(ws + o_hb);
    bf16*  agg2   = (bf16*)(ws + o_agg2);

    hipMemsetAsync(ws + o_deg, 0, o_segoff - o_deg, stream);

    {   // weights
        int total = NCAT * DIM + 2 * DIM * DIM;
        prep_weights<<<(total + 255) / 256, 256, 0, stream>>>(basis, comp, root, w_rel, w_root,
                                                              wcat, wrelT, wrootT);
    }
    {   // bf16 features (x4 vectorized)
        int n4 = N_NODES * DIM / 4;
        conv_x<<<(n4 + 255) / 256, 256, 0, stream>>>((const float4*)x, (ushort4*)xb, n4);
    }
    // counting sort by dst
    hist_kernel<<<(N_EDGES + 255) / 256, 256, 0, stream>>>(ei, deg);
    scan_blocks<<<SCAN_NB, 256, 0, stream>>>(deg, segoff, bsum, N_NODES);
    scan_sums<<<1, 64, 0, stream>>>(bsum, SCAN_NB);
    scan_add<<<SCAN_NB, 256, 0, stream>>>(segoff, bsum, N_NODES);
    scatter_kernel<<<(N_EDGES + 255) / 256, 256, 0, stream>>>(ei, et, en, segoff, cur, rec);

    // proj[N, 9*128] = xb @ WcatT^T  (row-panel blocks: A fetched once, staged epilogue)
    gemm1_kernel<<<(N_NODES + 63) / 64, 256, 0, stream>>>(xb, wcat, proj, N_NODES);
    // layer-1 gather (quarter-wave, ILP-4) -> h
    seg1_kernel<<<(N_NODES + 15) / 16, 256, 0, stream>>>(rec, segoff, (const ushort*)proj, bias1, (ushort*)hb);
    // layer-2 aggregation (quarter-wave, ILP-4)
    seg2_kernel<<<(N_NODES + 15) / 16, 256, 0, stream>>>(rec, segoff, (const ushort*)hb, (ushort*)agg2);
    // out = agg2 @ w_rel + h @ w_root + b_rel
    {
        dim3 grid((N_NODES + 63) / 64, DIM / 64);
        gemm2_kernel<<<grid, 256, 0, stream>>>(agg2, wrelT, hb, wrootT, b_rel, out, N_NODES);
    }
}

// Round 12
// 333.236 us; speedup vs baseline: 1.0330x; 1.0330x over previous
//
#include <hip/hip_runtime.h>
#include <hip/hip_bf16.h>
#include <stdint.h>

#define N_NODES 50000
#define N_EDGES 800000
#define NREL    8
#define NBASES  30
#define DIM     128
#define NSLOT   9                           // 8 relations + root
#define NCAT    (NSLOT*DIM)                 // 1152
#define SCAN_NB ((N_NODES + 255) / 256)     // 196 scan blocks (dst-only buckets)
#define GEMM1_TILES ((N_NODES + 63) / 64)   // 782
#define SCAT_BLKS   ((N_EDGES + 255) / 256) // 3125

typedef __attribute__((ext_vector_type(8))) short short8;
typedef __attribute__((ext_vector_type(4))) float floatx4;
typedef __hip_bfloat16  bf16;
typedef __hip_bfloat162 bf16x2;

__device__ inline ushort f2bu(float f) { bf16 b = __float2bfloat16(f); return *(ushort*)&b; }
__device__ inline float  bu2f(ushort u) { union { unsigned i; float f; } c; c.i = ((unsigned)u) << 16; return c.f; }

// ---------------- weight prep: WcatT[n][k], n = r*128+o (slot 8 = root); wrelT/wrootT[o][k] ----------------
__global__ void prep_weights(const float* __restrict__ basis, const float* __restrict__ comp,
                             const float* __restrict__ root, const float* __restrict__ w_rel,
                             const float* __restrict__ w_root,
                             bf16* __restrict__ WcatT, bf16* __restrict__ wrelT, bf16* __restrict__ wrootT) {
    int idx = blockIdx.x * blockDim.x + threadIdx.x;
    const int n_cat = NCAT * DIM;            // 147456
    const int n_sq  = DIM * DIM;             // 16384
    if (idx < n_cat) {
        int k = idx & 127, n = idx >> 7;
        int r = n >> 7, o = n & 127;
        float v;
        if (r < NREL) {
            v = 0.f;
            for (int b = 0; b < NBASES; ++b)
                v += comp[r * NBASES + b] * basis[(b * DIM + k) * DIM + o];
        } else {
            v = root[k * DIM + o];
        }
        WcatT[n * DIM + k] = __float2bfloat16(v);
    } else if (idx < n_cat + n_sq) {
        int t = idx - n_cat; int k = t & 127, o = t >> 7;
        wrelT[o * DIM + k] = __float2bfloat16(w_rel[k * DIM + o]);
    } else if (idx < n_cat + 2 * n_sq) {
        int t = idx - n_cat - n_sq; int k = t & 127, o = t >> 7;
        wrootT[o * DIM + k] = __float2bfloat16(w_root[k * DIM + o]);
    }
}

// ---------------- fp32 -> bf16 node features (vectorized x4) ----------------
__global__ void conv_x(const float4* __restrict__ x4, ushort4* __restrict__ xb4, int n4) {
    int i = blockIdx.x * blockDim.x + threadIdx.x;
    if (i < n4) {
        float4 f = x4[i];
        ushort4 o;
        o.x = f2bu(f.x); o.y = f2bu(f.y); o.z = f2bu(f.z); o.w = f2bu(f.w);
        xb4[i] = o;
    }
}

// ---------------- counting sort by dst (50k buckets) ----------------
__global__ void hist_kernel(const int* __restrict__ ei, int* __restrict__ deg) {
    int e = blockIdx.x * blockDim.x + threadIdx.x;
    if (e < N_EDGES) atomicAdd(&deg[ei[N_EDGES + e]], 1);
}

__global__ void scan_blocks(const int* __restrict__ deg, int* __restrict__ segoff,
                            int* __restrict__ bsum, int n) {
    __shared__ int buf[256];
    int tid = threadIdx.x;
    int i = blockIdx.x * 256 + tid;
    int v = (i < n) ? deg[i] : 0;
    buf[tid] = v;
    __syncthreads();
#pragma unroll
    for (int o = 1; o < 256; o <<= 1) {
        int t = (tid >= o) ? buf[tid - o] : 0;
        __syncthreads();
        buf[tid] += t;
        __syncthreads();
    }
    if (i < n) segoff[i + 1] = buf[tid];
    if (tid == 255) bsum[blockIdx.x] = buf[255];
}

// single WAVE shuffle-scan of block sums -> exclusive (no barriers)
__global__ void scan_sums(int* __restrict__ bsum, int nb) {
    int lane = threadIdx.x;   // 64 threads
    int base = 0;
    for (int start = 0; start < nb; start += 64) {
        int i = start + lane;
        int v = (i < nb) ? bsum[i] : 0;
        int incl = v;
#pragma unroll
        for (int o = 1; o < 64; o <<= 1) {
            int t = __shfl_up(incl, o, 64);
            if (lane >= o) incl += t;
        }
        if (i < nb) bsum[i] = base + incl - v;   // exclusive
        base += __shfl(incl, 63, 64);
    }
}

__global__ void scan_add(int* __restrict__ segoff, const int* __restrict__ bsum, int n) {
    int i = blockIdx.x * 256 + threadIdx.x;
    if (i < n) segoff[i + 1] += bsum[blockIdx.x];
    if (i == 0) segoff[0] = 0;
}

// ---------------- FUSED: gemm1 row-panel tiles + edge scatter, interleaved block roles ----------------
// Roles interleave 1:4 (gemm:scatter) by blockIdx so every CU hosts both concurrently:
// gemm tiles are write-BW/MFMA-bound, scatter chunks are atomic/latency-bound — independent work,
// previously 45.5 + 45.4 us serial on the stream.
// gemm: proj[M,1152] = xb[M,128] @ WcatT[1152,128]^T (A-panel staged once; direct fragment stores).
// scatter: rec[p] = (src | type<<16, norm) at p = segoff[dst] + cur[dst]++.
__global__ __launch_bounds__(256) void gemm1_scatter(const bf16* __restrict__ A, const bf16* __restrict__ BT,
                                                     bf16* __restrict__ C, int M,
                                                     const int* __restrict__ ei, const int* __restrict__ et,
                                                     const float* __restrict__ en, const int* __restrict__ segoff,
                                                     int* __restrict__ cur, uint2* __restrict__ rec) {
    __shared__ ushort As[64][136];
    __shared__ ushort Bs[64][136];
    int b = blockIdx.x;
    if (b % 5 == 0) {
        // ---- gemm role: tile b/5 in [0, 782) ----
        int tile = b / 5;
        const ushort* Au = (const ushort*)A;
        const ushort* Bu = (const ushort*)BT;
        ushort* Cu = (ushort*)C;
        int tm = tile * 64;
        int wave = threadIdx.x >> 6, lane = threadIdx.x & 63;
        int q = lane >> 4, mr = lane & 15;

        // stage A-panel once: 1024 short8 segs, 4/thread
#pragma unroll
        for (int u = 0; u < 4; ++u) {
            int cc = threadIdx.x + u * 256;
            int row = cc >> 4, seg = cc & 15;
            int gr = tm + row;
            short8 av = {0, 0, 0, 0, 0, 0, 0, 0};
            if (gr < M) av = *(const short8*)(Au + (size_t)gr * 128 + seg * 8);
            *(short8*)(&As[row][seg * 8]) = av;
        }

        floatx4 zero = {0.f, 0.f, 0.f, 0.f};
        for (int t = 0; t < 18; ++t) {
            if (t) __syncthreads();          // prior MFMA reads of Bs complete
            // stage B-tile (rows t*64..t*64+63 of WcatT): 1024 short8 segs, 4/thread
#pragma unroll
            for (int u = 0; u < 4; ++u) {
                int cc = threadIdx.x + u * 256;
                int row = cc >> 4, seg = cc & 15;
                short8 bv = *(const short8*)(Bu + (size_t)(t * 64 + row) * 128 + seg * 8);
                *(short8*)(&Bs[row][seg * 8]) = bv;
            }
            __syncthreads();
            floatx4 acc[4] = {zero, zero, zero, zero};
#pragma unroll
            for (int kt = 0; kt < 4; ++kt) {
                short8 a = *(const short8*)(&As[wave * 16 + mr][q * 8 + kt * 32]);
#pragma unroll
                for (int nt = 0; nt < 4; ++nt) {
                    short8 bb = *(const short8*)(&Bs[nt * 16 + mr][q * 8 + kt * 32]);
                    acc[nt] = __builtin_amdgcn_mfma_f32_16x16x32_bf16(a, bb, acc[nt], 0, 0, 0);
                }
            }
            // direct fragment stores for this 64x64 tile (R10 config — store path is the floor)
#pragma unroll
            for (int nt = 0; nt < 4; ++nt)
#pragma unroll
                for (int r4 = 0; r4 < 4; ++r4) {
                    int row = tm + wave * 16 + q * 4 + r4;
                    if (row < M) Cu[(size_t)row * NCAT + t * 64 + nt * 16 + mr] = f2bu(acc[nt][r4]);
                }
        }
    } else {
        // ---- scatter role: chunk sid in [0, 3125) ----
        int sid = b - (b / 5 + 1);
        int e = sid * 256 + threadIdx.x;
        if (e < N_EDGES) {
            int d = ei[N_EDGES + e];
            int p = segoff[d] + atomicAdd(&cur[d], 1);
            rec[p] = make_uint2((unsigned)ei[e] | ((unsigned)et[e] << 16), __float_as_uint(en[e]));
        }
    }
}

// ---------------- layer-1 gather: quarter-wave (16 lanes/node, 16 B/lane), ILP-4 ----------------
// h[node] = sum_e norm_e * proj[src_e, type_e] + proj[node, root-slot] + bias1
__global__ void seg1_kernel(const uint2* __restrict__ rec, const int* __restrict__ segoff,
                            const ushort* __restrict__ proj, const float* __restrict__ bias1,
                            ushort* __restrict__ h) {
    int quad = threadIdx.x >> 4;
    int node = blockIdx.x * 16 + quad;
    if (node >= N_NODES) return;
    int lane = threadIdx.x & 15;
    int s = segoff[node], e = segoff[node + 1];
    float acc[8] = {0.f, 0.f, 0.f, 0.f, 0.f, 0.f, 0.f, 0.f};
    for (int chunk = s; chunk < e; chunk += 4) {
        int m = e - chunk; if (m > 4) m = 4;
        uint2 rr[4]; short8 vv[4];
#pragma unroll
        for (int j = 0; j < 4; ++j) if (j < m) rr[j] = rec[chunk + j];
#pragma unroll
        for (int j = 0; j < 4; ++j) if (j < m) {
            unsigned src = rr[j].x & 0xFFFFu;
            unsigned typ = rr[j].x >> 16;
            vv[j] = *(const short8*)(proj + ((size_t)src * NSLOT + typ) * 128 + lane * 8);
        }
#pragma unroll
        for (int j = 0; j < 4; ++j) if (j < m) {
            float norm = __uint_as_float(rr[j].y);
#pragma unroll
            for (int f = 0; f < 8; ++f) acc[f] += norm * bu2f((ushort)vv[j][f]);
        }
    }
    short8 base = *(const short8*)(proj + ((size_t)node * NSLOT + 8) * 128 + lane * 8);
    short8 o;
#pragma unroll
    for (int f = 0; f < 8; ++f)
        o[f] = (short)f2bu(acc[f] + bu2f((ushort)base[f]) + bias1[lane * 8 + f]);
    *(short8*)(h + (size_t)node * 128 + lane * 8) = o;
}

// ---------------- layer-2 segment sum: quarter-wave, ILP-4 ----------------
__global__ void seg2_kernel(const uint2* __restrict__ rec, const int* __restrict__ segoff,
                            const ushort* __restrict__ h, ushort* __restrict__ out2) {
    int quad = threadIdx.x >> 4;
    int node = blockIdx.x * 16 + quad;
    if (node >= N_NODES) return;
    int lane = threadIdx.x & 15;
    int s = segoff[node], e = segoff[node + 1];
    float acc[8] = {0.f, 0.f, 0.f, 0.f, 0.f, 0.f, 0.f, 0.f};
    for (int chunk = s; chunk < e; chunk += 4) {
        int m = e - chunk; if (m > 4) m = 4;
        uint2 rr[4]; short8 vv[4];
#pragma unroll
        for (int j = 0; j < 4; ++j) if (j < m) rr[j] = rec[chunk + j];
#pragma unroll
        for (int j = 0; j < 4; ++j) if (j < m)
            vv[j] = *(const short8*)(h + (size_t)(rr[j].x & 0xFFFFu) * 128 + lane * 8);
#pragma unroll
        for (int j = 0; j < 4; ++j) if (j < m)
#pragma unroll
            for (int f = 0; f < 8; ++f) acc[f] += bu2f((ushort)vv[j][f]);
    }
    short8 o;
#pragma unroll
    for (int f = 0; f < 8; ++f) o[f] = (short)f2bu(acc[f]);
    *(short8*)(out2 + (size_t)node * 128 + lane * 8) = o;
}

// ---------------- final GEMM: out[M,128](f32) = agg2nd@w_rel + h@w_root + b_rel ----------------
// Epilogue: stage f32 C-tile in LDS (reuse As as float[64][68]), then float4 full-line stores.
__global__ __launch_bounds__(256) void gemm2_kernel(const bf16* __restrict__ A1, const bf16* __restrict__ B1T,
                                                    const bf16* __restrict__ A2, const bf16* __restrict__ B2T,
                                                    const float* __restrict__ brel, float* __restrict__ out, int M) {
    __shared__ ushort As[64][136];
    __shared__ ushort Bs[64][136];
    int tm = blockIdx.x * 64, tn = blockIdx.y * 64;
    int wave = threadIdx.x >> 6, lane = threadIdx.x & 63;
    int q = lane >> 4, mr = lane & 15;
    floatx4 zero = {0.f, 0.f, 0.f, 0.f};
    floatx4 acc[4] = {zero, zero, zero, zero};

    for (int phase = 0; phase < 2; ++phase) {
        const ushort* Au = (const ushort*)(phase ? A2 : A1);
        const ushort* Bu = (const ushort*)(phase ? B2T : B1T);
        if (phase) __syncthreads();
        for (int c = threadIdx.x; c < 64 * 16; c += 256) {
            int row = c >> 4, seg = c & 15;
            int gr = tm + row;
            short8 av = {0, 0, 0, 0, 0, 0, 0, 0};
            if (gr < M) av = *(const short8*)(Au + (size_t)gr * 128 + seg * 8);
            *(short8*)(&As[row][seg * 8]) = av;
            short8 bv = *(const short8*)(Bu + (size_t)(tn + row) * 128 + seg * 8);
            *(short8*)(&Bs[row][seg * 8]) = bv;
        }
        __syncthreads();
#pragma unroll
        for (int kt = 0; kt < 4; ++kt) {
            short8 a = *(const short8*)(&As[wave * 16 + mr][q * 8 + kt * 32]);
#pragma unroll
            for (int nt = 0; nt < 4; ++nt) {
                short8 b = *(const short8*)(&Bs[nt * 16 + mr][q * 8 + kt * 32]);
                acc[nt] = __builtin_amdgcn_mfma_f32_16x16x32_bf16(a, b, acc[nt], 0, 0, 0);
            }
        }
    }
    // ---- epilogue: fragment (+bias) -> LDS floats (stride 68 = 272 B, fills As exactly) ----
    __syncthreads();
    float* Csf = (float*)&As[0][0];
#pragma unroll
    for (int nt = 0; nt < 4; ++nt)
#pragma unroll
        for (int r4 = 0; r4 < 4; ++r4) {
            int row = wave * 16 + q * 4 + r4;
            int col = nt * 16 + mr;
            Csf[row * 68 + col] = acc[nt][r4] + brel[tn + col];
        }
    __syncthreads();
    // cooperative float4 full-line stores: 1024 segs, 4/thread; 16 lanes = one 256 B row-slice
#pragma unroll
    for (int u = 0; u < 4; ++u) {
        int cc = threadIdx.x + u * 256;
        int row = cc >> 4, seg = cc & 15;
        int gr = tm + row;
        if (gr < M) {
            float4 v = *(const float4*)(&Csf[row * 68 + seg * 4]);
            *(float4*)(out + (size_t)gr * 128 + tn + seg * 4) = v;
        }
    }
}

extern "C" void kernel_launch(void* const* d_in, const int* in_sizes, int n_in,
                              void* d_out, int out_size, void* d_ws, size_t ws_size,
                              hipStream_t stream) {
    const float* x      = (const float*)d_in[0];
    const int*   ei     = (const int*)d_in[1];
    const int*   et     = (const int*)d_in[2];
    const float* en     = (const float*)d_in[3];
    const float* basis  = (const float*)d_in[4];
    const float* comp   = (const float*)d_in[5];
    const float* root   = (const float*)d_in[6];
    const float* bias1  = (const float*)d_in[7];
    const float* w_rel  = (const float*)d_in[8];
    const float* b_rel  = (const float*)d_in[9];
    const float* w_root = (const float*)d_in[10];
    float* out = (float*)d_out;

    char* ws = (char*)d_ws;
    size_t off = 0;
    auto alloc = [&](size_t bytes) { size_t o = off; off += (bytes + 255) & ~(size_t)255; return o; };

    size_t o_deg    = alloc((size_t)N_NODES * 4);        // zeroed
    size_t o_cur    = alloc((size_t)N_NODES * 4);        // zeroed (contiguous with deg)
    size_t o_segoff = alloc((size_t)(N_NODES + 1) * 4);
    size_t o_bsum   = alloc((size_t)SCAN_NB * 4);
    size_t o_rec    = alloc((size_t)N_EDGES * 8);
    size_t o_wcat   = alloc((size_t)NCAT * DIM * 2);
    size_t o_wrel   = alloc((size_t)DIM * DIM * 2);
    size_t o_wroot  = alloc((size_t)DIM * DIM * 2);
    size_t o_xb     = alloc((size_t)N_NODES * DIM * 2);
    size_t o_proj   = alloc((size_t)N_NODES * NCAT * 2); // 115.2 MB
    size_t o_hb     = alloc((size_t)N_NODES * DIM * 2);
    size_t o_agg2   = alloc((size_t)N_NODES * DIM * 2);

    int*   deg    = (int*)(ws + o_deg);
    int*   cur    = (int*)(ws + o_cur);
    int*   segoff = (int*)(ws + o_segoff);
    int*   bsum   = (int*)(ws + o_bsum);
    uint2* rec    = (uint2*)(ws + o_rec);
    bf16*  wcat   = (bf16*)(ws + o_wcat);
    bf16*  wrelT  = (bf16*)(ws + o_wrel);
    bf16*  wrootT = (bf16*)(ws + o_wroot);
    bf16*  xb     = (bf16*)(ws + o_xb);
    bf16*  proj   = (bf16*)(ws + o_proj);
    bf16*  hb     = (bf16*)(ws + o_hb);
    bf16*  agg2   = (bf16*)(ws + o_agg2);

    hipMemsetAsync(ws + o_deg, 0, o_segoff - o_deg, stream);

    {   // weights
        int total = NCAT * DIM + 2 * DIM * DIM;
        prep_weights<<<(total + 255) / 256, 256, 0, stream>>>(basis, comp, root, w_rel, w_root,
                                                              wcat, wrelT, wrootT);
    }
    {   // bf16 features (x4 vectorized)
        int n4 = N_NODES * DIM / 4;
        conv_x<<<(n4 + 255) / 256, 256, 0, stream>>>((const float4*)x, (ushort4*)xb, n4);
    }
    // counting sort by dst (hist + scan; payload scatter fused with gemm1 below)
    hist_kernel<<<(N_EDGES + 255) / 256, 256, 0, stream>>>(ei, deg);
    scan_blocks<<<SCAN_NB, 256, 0, stream>>>(deg, segoff, bsum, N_NODES);
    scan_sums<<<1, 64, 0, stream>>>(bsum, SCAN_NB);
    scan_add<<<SCAN_NB, 256, 0, stream>>>(segoff, bsum, N_NODES);

    // fused: proj = xb @ WcatT^T  +  edge scatter (independent work, interleaved 1:4)
    gemm1_scatter<<<GEMM1_TILES + SCAT_BLKS, 256, 0, stream>>>(xb, wcat, proj, N_NODES,
                                                               ei, et, en, segoff, cur, rec);
    // layer-1 gather (quarter-wave, ILP-4) -> h
    seg1_kernel<<<(N_NODES + 15) / 16, 256, 0, stream>>>(rec, segoff, (const ushort*)proj, bias1, (ushort*)hb);
    // layer-2 aggregation (quarter-wave, ILP-4)
    seg2_kernel<<<(N_NODES + 15) / 16, 256, 0, stream>>>(rec, segoff, (const ushort*)hb, (ushort*)agg2);
    // out = agg2 @ w_rel + h @ w_root + b_rel
    {
        dim3 grid((N_NODES + 63) / 64, DIM / 64);
        gemm2_kernel<<<grid, 256, 0, stream>>>(agg2, wrelT, hb, wrootT, b_rel, out, N_NODES);
    }
}

// Round 13
// 328.645 us; speedup vs baseline: 1.0475x; 1.0140x over previous
//
#include <hip/hip_runtime.h>
#include <hip/hip_bf16.h>
#include <stdint.h>

#define N_NODES 50000
#define N_EDGES 800000
#define NREL    8
#define NBASES  30
#define DIM     128
#define NSLOT   9                           // 8 relations + root
#define NCAT    (NSLOT*DIM)                 // 1152
#define SCAN_NB ((N_NODES + 255) / 256)     // 196 scan blocks (dst-only buckets)
#define NB_C    196                         // coarse buckets (dst >> 8)
#define EPB_PLACE 2048
#define NBLK_PLACE ((N_EDGES + EPB_PLACE - 1) / EPB_PLACE)   // 391

typedef __attribute__((ext_vector_type(8))) short short8;
typedef __attribute__((ext_vector_type(4))) float floatx4;
typedef __hip_bfloat16  bf16;
typedef __hip_bfloat162 bf16x2;

__device__ inline ushort f2bu(float f) { bf16 b = __float2bfloat16(f); return *(ushort*)&b; }
__device__ inline float  bu2f(ushort u) { union { unsigned i; float f; } c; c.i = ((unsigned)u) << 16; return c.f; }

// ---------------- weight prep: WcatT[n][k], n = r*128+o (slot 8 = root); wrelT/wrootT[o][k] ----------------
__global__ void prep_weights(const float* __restrict__ basis, const float* __restrict__ comp,
                             const float* __restrict__ root, const float* __restrict__ w_rel,
                             const float* __restrict__ w_root,
                             bf16* __restrict__ WcatT, bf16* __restrict__ wrelT, bf16* __restrict__ wrootT) {
    int idx = blockIdx.x * blockDim.x + threadIdx.x;
    const int n_cat = NCAT * DIM;            // 147456
    const int n_sq  = DIM * DIM;             // 16384
    if (idx < n_cat) {
        int k = idx & 127, n = idx >> 7;
        int r = n >> 7, o = n & 127;
        float v;
        if (r < NREL) {
            v = 0.f;
            for (int b = 0; b < NBASES; ++b)
                v += comp[r * NBASES + b] * basis[(b * DIM + k) * DIM + o];
        } else {
            v = root[k * DIM + o];
        }
        WcatT[n * DIM + k] = __float2bfloat16(v);
    } else if (idx < n_cat + n_sq) {
        int t = idx - n_cat; int k = t & 127, o = t >> 7;
        wrelT[o * DIM + k] = __float2bfloat16(w_rel[k * DIM + o]);
    } else if (idx < n_cat + 2 * n_sq) {
        int t = idx - n_cat - n_sq; int k = t & 127, o = t >> 7;
        wrootT[o * DIM + k] = __float2bfloat16(w_root[k * DIM + o]);
    }
}

// ---------------- fp32 -> bf16 node features (vectorized x4) ----------------
__global__ void conv_x(const float4* __restrict__ x4, ushort4* __restrict__ xb4, int n4) {
    int i = blockIdx.x * blockDim.x + threadIdx.x;
    if (i < n4) {
        float4 f = x4[i];
        ushort4 o;
        o.x = f2bu(f.x); o.y = f2bu(f.y); o.z = f2bu(f.z); o.w = f2bu(f.w);
        xb4[i] = o;
    }
}

// ---------------- fine histogram by dst (50k buckets) ----------------
__global__ void hist_kernel(const int* __restrict__ ei, int* __restrict__ deg) {
    int e = blockIdx.x * blockDim.x + threadIdx.x;
    if (e < N_EDGES) atomicAdd(&deg[ei[N_EDGES + e]], 1);
}

__global__ void scan_blocks(const int* __restrict__ deg, int* __restrict__ segoff,
                            int* __restrict__ bsum, int n) {
    __shared__ int buf[256];
    int tid = threadIdx.x;
    int i = blockIdx.x * 256 + tid;
    int v = (i < n) ? deg[i] : 0;
    buf[tid] = v;
    __syncthreads();
#pragma unroll
    for (int o = 1; o < 256; o <<= 1) {
        int t = (tid >= o) ? buf[tid - o] : 0;
        __syncthreads();
        buf[tid] += t;
        __syncthreads();
    }
    if (i < n) segoff[i + 1] = buf[tid];
    if (tid == 255) bsum[blockIdx.x] = buf[255];
}

// single WAVE shuffle-scan of block sums -> exclusive (no barriers)
__global__ void scan_sums(int* __restrict__ bsum, int nb) {
    int lane = threadIdx.x;   // 64 threads
    int base = 0;
    for (int start = 0; start < nb; start += 64) {
        int i = start + lane;
        int v = (i < nb) ? bsum[i] : 0;
        int incl = v;
#pragma unroll
        for (int o = 1; o < 64; o <<= 1) {
            int t = __shfl_up(incl, o, 64);
            if (lane >= o) incl += t;
        }
        if (i < nb) bsum[i] = base + incl - v;   // exclusive
        base += __shfl(incl, 63, 64);
    }
}

__global__ void scan_add(int* __restrict__ segoff, const int* __restrict__ bsum, int n) {
    int i = blockIdx.x * 256 + threadIdx.x;
    if (i < n) segoff[i + 1] += bsum[blockIdx.x];
    if (i == 0) segoff[0] = 0;
}

// ---------------- sort pass A: place edges into coarse-bucket regions (run-reserved, low write amp) ----------------
// tmp.x = src | type<<16 | (dst&255)<<19 ; tmp.y = norm bits. Bucket c region = [segoff[c<<8], ...).
__global__ __launch_bounds__(256) void place_kernel(const int* __restrict__ ei, const int* __restrict__ et,
                                                    const float* __restrict__ en, const int* __restrict__ segoff,
                                                    int* __restrict__ bcur, uint2* __restrict__ tmp) {
    __shared__ int lhist[NB_C];
    __shared__ int lbase[NB_C];
    __shared__ int lrank[NB_C];
    int tid = threadIdx.x;
    for (int i = tid; i < NB_C; i += 256) { lhist[i] = 0; lrank[i] = 0; }
    __syncthreads();
    int e0 = blockIdx.x * EPB_PLACE;
#pragma unroll
    for (int i = 0; i < EPB_PLACE / 256; ++i) {
        int e = e0 + i * 256 + tid;
        if (e < N_EDGES) atomicAdd(&lhist[ei[N_EDGES + e] >> 8], 1);
    }
    __syncthreads();
    // reserve one contiguous run per (block, bucket)
    for (int c = tid; c < NB_C; c += 256)
        if (lhist[c] > 0) lbase[c] = atomicAdd(&bcur[c], lhist[c]);
    __syncthreads();
#pragma unroll
    for (int i = 0; i < EPB_PLACE / 256; ++i) {
        int e = e0 + i * 256 + tid;
        if (e < N_EDGES) {
            int d = ei[N_EDGES + e];
            int c = d >> 8;
            int r = atomicAdd(&lrank[c], 1);
            int p = segoff[c << 8] + lbase[c] + r;
            tmp[p] = make_uint2((unsigned)ei[e] | ((unsigned)et[e] << 16) | ((unsigned)(d & 255) << 19),
                                __float_as_uint(en[e]));
        }
    }
}

// ---------------- sort pass B: finalize order within each coarse bucket (all writes block-local) ----------------
__global__ __launch_bounds__(256) void sortb_kernel(const uint2* __restrict__ tmp, const int* __restrict__ segoff,
                                                    uint2* __restrict__ rec) {
    __shared__ int cur[256];
    int c = blockIdx.x;               // 0..195
    int tid = threadIdx.x;
    cur[tid] = 0;
    __syncthreads();
    int base = segoff[c << 8];
    int nlimit = (c + 1) << 8; if (nlimit > N_NODES) nlimit = N_NODES;
    int end = segoff[nlimit];
    for (int i = base + tid; i < end; i += 256) {
        uint2 r = tmp[i];
        int dl = (r.x >> 19) & 255;
        int p = segoff[(c << 8) + dl] + atomicAdd(&cur[dl], 1);
        rec[p] = make_uint2(r.x & 0x7FFFFu, r.y);   // keep src(16) + type(3)
    }
}

// ---------------- MFMA GEMM (row-panel): proj[M,1152] = xb[M,128] @ WcatT[1152,128]^T ----------------
// Block stages its 64x128 A-panel ONCE, then loops the 18 B-tiles (wcat stays L2-resident).
// Direct fragment stores (R11 showed the LDS-staged epilogue regresses; write path is the floor).
__global__ __launch_bounds__(256) void gemm1_kernel(const bf16* __restrict__ A, const bf16* __restrict__ BT,
                                                    bf16* __restrict__ C, int M) {
    __shared__ ushort As[64][136];
    __shared__ ushort Bs[64][136];
    const ushort* Au = (const ushort*)A;
    const ushort* Bu = (const ushort*)BT;
    ushort* Cu = (ushort*)C;
    int tm = blockIdx.x * 64;
    int wave = threadIdx.x >> 6, lane = threadIdx.x & 63;
    int q = lane >> 4, mr = lane & 15;

    // stage A-panel once: 1024 short8 segs, 4/thread
#pragma unroll
    for (int u = 0; u < 4; ++u) {
        int cc = threadIdx.x + u * 256;
        int row = cc >> 4, seg = cc & 15;
        int gr = tm + row;
        short8 av = {0, 0, 0, 0, 0, 0, 0, 0};
        if (gr < M) av = *(const short8*)(Au + (size_t)gr * 128 + seg * 8);
        *(short8*)(&As[row][seg * 8]) = av;
    }

    floatx4 zero = {0.f, 0.f, 0.f, 0.f};
    for (int t = 0; t < 18; ++t) {
        if (t) __syncthreads();          // prior MFMA reads of Bs complete
#pragma unroll
        for (int u = 0; u < 4; ++u) {
            int cc = threadIdx.x + u * 256;
            int row = cc >> 4, seg = cc & 15;
            short8 bv = *(const short8*)(Bu + (size_t)(t * 64 + row) * 128 + seg * 8);
            *(short8*)(&Bs[row][seg * 8]) = bv;
        }
        __syncthreads();
        floatx4 acc[4] = {zero, zero, zero, zero};
#pragma unroll
        for (int kt = 0; kt < 4; ++kt) {
            short8 a = *(const short8*)(&As[wave * 16 + mr][q * 8 + kt * 32]);
#pragma unroll
            for (int nt = 0; nt < 4; ++nt) {
                short8 b = *(const short8*)(&Bs[nt * 16 + mr][q * 8 + kt * 32]);
                acc[nt] = __builtin_amdgcn_mfma_f32_16x16x32_bf16(a, b, acc[nt], 0, 0, 0);
            }
        }
#pragma unroll
        for (int nt = 0; nt < 4; ++nt)
#pragma unroll
            for (int r4 = 0; r4 < 4; ++r4) {
                int row = tm + wave * 16 + q * 4 + r4;
                if (row < M) Cu[(size_t)row * NCAT + t * 64 + nt * 16 + mr] = f2bu(acc[nt][r4]);
            }
    }
}

// ---------------- layer-1 gather: quarter-wave (16 lanes/node, 16 B/lane), ILP-4 ----------------
// h[node] = sum_e norm_e * proj[src_e, type_e] + proj[node, root-slot] + bias1
__global__ void seg1_kernel(const uint2* __restrict__ rec, const int* __restrict__ segoff,
                            const ushort* __restrict__ proj, const float* __restrict__ bias1,
                            ushort* __restrict__ h) {
    int quad = threadIdx.x >> 4;
    int node = blockIdx.x * 16 + quad;
    if (node >= N_NODES) return;
    int lane = threadIdx.x & 15;
    int s = segoff[node], e = segoff[node + 1];
    float acc[8] = {0.f, 0.f, 0.f, 0.f, 0.f, 0.f, 0.f, 0.f};
    for (int chunk = s; chunk < e; chunk += 4) {
        int m = e - chunk; if (m > 4) m = 4;
        uint2 rr[4]; short8 vv[4];
#pragma unroll
        for (int j = 0; j < 4; ++j) if (j < m) rr[j] = rec[chunk + j];
#pragma unroll
        for (int j = 0; j < 4; ++j) if (j < m) {
            unsigned src = rr[j].x & 0xFFFFu;
            unsigned typ = rr[j].x >> 16;
            vv[j] = *(const short8*)(proj + ((size_t)src * NSLOT + typ) * 128 + lane * 8);
        }
#pragma unroll
        for (int j = 0; j < 4; ++j) if (j < m) {
            float norm = __uint_as_float(rr[j].y);
#pragma unroll
            for (int f = 0; f < 8; ++f) acc[f] += norm * bu2f((ushort)vv[j][f]);
        }
    }
    short8 base = *(const short8*)(proj + ((size_t)node * NSLOT + 8) * 128 + lane * 8);
    short8 o;
#pragma unroll
    for (int f = 0; f < 8; ++f)
        o[f] = (short)f2bu(acc[f] + bu2f((ushort)base[f]) + bias1[lane * 8 + f]);
    *(short8*)(h + (size_t)node * 128 + lane * 8) = o;
}

// ---------------- layer-2 segment sum: quarter-wave, ILP-4 ----------------
__global__ void seg2_kernel(const uint2* __restrict__ rec, const int* __restrict__ segoff,
                            const ushort* __restrict__ h, ushort* __restrict__ out2) {
    int quad = threadIdx.x >> 4;
    int node = blockIdx.x * 16 + quad;
    if (node >= N_NODES) return;
    int lane = threadIdx.x & 15;
    int s = segoff[node], e = segoff[node + 1];
    float acc[8] = {0.f, 0.f, 0.f, 0.f, 0.f, 0.f, 0.f, 0.f};
    for (int chunk = s; chunk < e; chunk += 4) {
        int m = e - chunk; if (m > 4) m = 4;
        uint2 rr[4]; short8 vv[4];
#pragma unroll
        for (int j = 0; j < 4; ++j) if (j < m) rr[j] = rec[chunk + j];
#pragma unroll
        for (int j = 0; j < 4; ++j) if (j < m)
            vv[j] = *(const short8*)(h + (size_t)(rr[j].x & 0xFFFFu) * 128 + lane * 8);
#pragma unroll
        for (int j = 0; j < 4; ++j) if (j < m)
#pragma unroll
            for (int f = 0; f < 8; ++f) acc[f] += bu2f((ushort)vv[j][f]);
    }
    short8 o;
#pragma unroll
    for (int f = 0; f < 8; ++f) o[f] = (short)f2bu(acc[f]);
    *(short8*)(out2 + (size_t)node * 128 + lane * 8) = o;
}

// ---------------- final GEMM: out[M,128](f32) = agg2nd@w_rel + h@w_root + b_rel ----------------
// Epilogue: stage f32 C-tile in LDS (reuse As as float[64][68]), then float4 full-line stores.
__global__ __launch_bounds__(256) void gemm2_kernel(const bf16* __restrict__ A1, const bf16* __restrict__ B1T,
                                                    const bf16* __restrict__ A2, const bf16* __restrict__ B2T,
                                                    const float* __restrict__ brel, float* __restrict__ out, int M) {
    __shared__ ushort As[64][136];
    __shared__ ushort Bs[64][136];
    int tm = blockIdx.x * 64, tn = blockIdx.y * 64;
    int wave = threadIdx.x >> 6, lane = threadIdx.x & 63;
    int q = lane >> 4, mr = lane & 15;
    floatx4 zero = {0.f, 0.f, 0.f, 0.f};
    floatx4 acc[4] = {zero, zero, zero, zero};

    for (int phase = 0; phase < 2; ++phase) {
        const ushort* Au = (const ushort*)(phase ? A2 : A1);
        const ushort* Bu = (const ushort*)(phase ? B2T : B1T);
        if (phase) __syncthreads();
        for (int c = threadIdx.x; c < 64 * 16; c += 256) {
            int row = c >> 4, seg = c & 15;
            int gr = tm + row;
            short8 av = {0, 0, 0, 0, 0, 0, 0, 0};
            if (gr < M) av = *(const short8*)(Au + (size_t)gr * 128 + seg * 8);
            *(short8*)(&As[row][seg * 8]) = av;
            short8 bv = *(const short8*)(Bu + (size_t)(tn + row) * 128 + seg * 8);
            *(short8*)(&Bs[row][seg * 8]) = bv;
        }
        __syncthreads();
#pragma unroll
        for (int kt = 0; kt < 4; ++kt) {
            short8 a = *(const short8*)(&As[wave * 16 + mr][q * 8 + kt * 32]);
#pragma unroll
            for (int nt = 0; nt < 4; ++nt) {
                short8 b = *(const short8*)(&Bs[nt * 16 + mr][q * 8 + kt * 32]);
                acc[nt] = __builtin_amdgcn_mfma_f32_16x16x32_bf16(a, b, acc[nt], 0, 0, 0);
            }
        }
    }
    // ---- epilogue: fragment (+bias) -> LDS floats (stride 68 = 272 B, fills As exactly) ----
    __syncthreads();
    float* Csf = (float*)&As[0][0];
#pragma unroll
    for (int nt = 0; nt < 4; ++nt)
#pragma unroll
        for (int r4 = 0; r4 < 4; ++r4) {
            int row = wave * 16 + q * 4 + r4;
            int col = nt * 16 + mr;
            Csf[row * 68 + col] = acc[nt][r4] + brel[tn + col];
        }
    __syncthreads();
    // cooperative float4 full-line stores: 1024 segs, 4/thread; 16 lanes = one 256 B row-slice
#pragma unroll
    for (int u = 0; u < 4; ++u) {
        int cc = threadIdx.x + u * 256;
        int row = cc >> 4, seg = cc & 15;
        int gr = tm + row;
        if (gr < M) {
            float4 v = *(const float4*)(&Csf[row * 68 + seg * 4]);
            *(float4*)(out + (size_t)gr * 128 + tn + seg * 4) = v;
        }
    }
}

extern "C" void kernel_launch(void* const* d_in, const int* in_sizes, int n_in,
                              void* d_out, int out_size, void* d_ws, size_t ws_size,
                              hipStream_t stream) {
    const float* x      = (const float*)d_in[0];
    const int*   ei     = (const int*)d_in[1];
    const int*   et     = (const int*)d_in[2];
    const float* en     = (const float*)d_in[3];
    const float* basis  = (const float*)d_in[4];
    const float* comp   = (const float*)d_in[5];
    const float* root   = (const float*)d_in[6];
    const float* bias1  = (const float*)d_in[7];
    const float* w_rel  = (const float*)d_in[8];
    const float* b_rel  = (const float*)d_in[9];
    const float* w_root = (const float*)d_in[10];
    float* out = (float*)d_out;

    char* ws = (char*)d_ws;
    size_t off = 0;
    auto alloc = [&](size_t bytes) { size_t o = off; off += (bytes + 255) & ~(size_t)255; return o; };

    size_t o_deg    = alloc((size_t)N_NODES * 4);        // zeroed
    size_t o_bcur   = alloc((size_t)NB_C * 4);           // zeroed (contiguous with deg)
    size_t o_segoff = alloc((size_t)(N_NODES + 1) * 4);
    size_t o_bsum   = alloc((size_t)SCAN_NB * 4);
    size_t o_rec    = alloc((size_t)N_EDGES * 8);
    size_t o_tmp    = alloc((size_t)N_EDGES * 8);
    size_t o_wcat   = alloc((size_t)NCAT * DIM * 2);
    size_t o_wrel   = alloc((size_t)DIM * DIM * 2);
    size_t o_wroot  = alloc((size_t)DIM * DIM * 2);
    size_t o_xb     = alloc((size_t)N_NODES * DIM * 2);
    size_t o_proj   = alloc((size_t)N_NODES * NCAT * 2); // 115.2 MB
    size_t o_hb     = alloc((size_t)N_NODES * DIM * 2);
    size_t o_agg2   = alloc((size_t)N_NODES * DIM * 2);

    int*   deg    = (int*)(ws + o_deg);
    int*   bcur   = (int*)(ws + o_bcur);
    int*   segoff = (int*)(ws + o_segoff);
    int*   bsum   = (int*)(ws + o_bsum);
    uint2* rec    = (uint2*)(ws + o_rec);
    uint2* tmp    = (uint2*)(ws + o_tmp);
    bf16*  wcat   = (bf16*)(ws + o_wcat);
    bf16*  wrelT  = (bf16*)(ws + o_wrel);
    bf16*  wrootT = (bf16*)(ws + o_wroot);
    bf16*  xb     = (bf16*)(ws + o_xb);
    bf16*  proj   = (bf16*)(ws + o_proj);
    bf16*  hb     = (bf16*)(ws + o_hb);
    bf16*  agg2   = (bf16*)(ws + o_agg2);

    // zero deg + bcur (contiguous padded region)
    hipMemsetAsync(ws + o_deg, 0, o_segoff - o_deg, stream);

    {   // weights
        int total = NCAT * DIM + 2 * DIM * DIM;
        prep_weights<<<(total + 255) / 256, 256, 0, stream>>>(basis, comp, root, w_rel, w_root,
                                                              wcat, wrelT, wrootT);
    }
    {   // bf16 features (x4 vectorized)
        int n4 = N_NODES * DIM / 4;
        conv_x<<<(n4 + 255) / 256, 256, 0, stream>>>((const float4*)x, (ushort4*)xb, n4);
    }
    // fine histogram + prefix scan
    hist_kernel<<<(N_EDGES + 255) / 256, 256, 0, stream>>>(ei, deg);
    scan_blocks<<<SCAN_NB, 256, 0, stream>>>(deg, segoff, bsum, N_NODES);
    scan_sums<<<1, 64, 0, stream>>>(bsum, SCAN_NB);
    scan_add<<<SCAN_NB, 256, 0, stream>>>(segoff, bsum, N_NODES);
    // two-pass bucket sort (low write amplification)
    place_kernel<<<NBLK_PLACE, 256, 0, stream>>>(ei, et, en, segoff, bcur, tmp);
    sortb_kernel<<<NB_C, 256, 0, stream>>>(tmp, segoff, rec);

    // proj[N, 9*128] = xb @ WcatT^T  (row-panel blocks: A fetched once)
    gemm1_kernel<<<(N_NODES + 63) / 64, 256, 0, stream>>>(xb, wcat, proj, N_NODES);
    // layer-1 gather (quarter-wave, ILP-4) -> h
    seg1_kernel<<<(N_NODES + 15) / 16, 256, 0, stream>>>(rec, segoff, (const ushort*)proj, bias1, (ushort*)hb);
    // layer-2 aggregation (quarter-wave, ILP-4)
    seg2_kernel<<<(N_NODES + 15) / 16, 256, 0, stream>>>(rec, segoff, (const ushort*)hb, (ushort*)agg2);
    // out = agg2 @ w_rel + h @ w_root + b_rel
    {
        dim3 grid((N_NODES + 63) / 64, DIM / 64);
        gemm2_kernel<<<grid, 256, 0, stream>>>(agg2, wrelT, hb, wrootT, b_rel, out, N_NODES);
    }
}

// Round 14
// 326.774 us; speedup vs baseline: 1.0535x; 1.0057x over previous
//
#include <hip/hip_runtime.h>
#include <hip/hip_bf16.h>
#include <stdint.h>

#define N_NODES 50000
#define N_EDGES 800000
#define NREL    8
#define NBASES  30
#define DIM     128
#define NSLOT   9                           // 8 relations + root
#define NCAT    (NSLOT*DIM)                 // 1152
#define SCAN_NB ((N_NODES + 255) / 256)     // 196 scan blocks
#define NB_C    196                         // coarse buckets (dst >> 8)
#define EPB_PLACE 2048
#define NBLK_PLACE ((N_EDGES + EPB_PLACE - 1) / EPB_PLACE)   // 391
#define GEMM1_TILES ((N_NODES + 63) / 64)   // 782
#define PREP_TOTAL  (NCAT * DIM + 2 * DIM * DIM)             // 180224
#define PREP_BLKS   ((PREP_TOTAL + 255) / 256)               // 704
#define CONV_BLKS   ((N_NODES * DIM / 4 + 255) / 256)        // 6250
#define HIST_BLKS   ((N_EDGES + 255) / 256)                  // 3125

typedef __attribute__((ext_vector_type(8))) short short8;
typedef __attribute__((ext_vector_type(4))) float floatx4;
typedef __hip_bfloat16  bf16;
typedef __hip_bfloat162 bf16x2;

__device__ inline ushort f2bu(float f) { bf16 b = __float2bfloat16(f); return *(ushort*)&b; }
__device__ inline float  bu2f(ushort u) { union { unsigned i; float f; } c; c.i = ((unsigned)u) << 16; return c.f; }

// ---------------- SETUP (merged): prep_weights | conv_x | hist, role by block range ----------------
__global__ __launch_bounds__(256) void setup_kernel(const float* __restrict__ basis, const float* __restrict__ comp,
                                                    const float* __restrict__ root, const float* __restrict__ w_rel,
                                                    const float* __restrict__ w_root,
                                                    bf16* __restrict__ WcatT, bf16* __restrict__ wrelT,
                                                    bf16* __restrict__ wrootT,
                                                    const float4* __restrict__ x4, ushort4* __restrict__ xb4,
                                                    const int* __restrict__ ei, int* __restrict__ deg) {
    int b = blockIdx.x;
    if (b < PREP_BLKS) {
        int idx = b * 256 + threadIdx.x;
        const int n_cat = NCAT * DIM;
        const int n_sq  = DIM * DIM;
        if (idx < n_cat) {
            int k = idx & 127, n = idx >> 7;
            int r = n >> 7, o = n & 127;
            float v;
            if (r < NREL) {
                v = 0.f;
                for (int bb = 0; bb < NBASES; ++bb)
                    v += comp[r * NBASES + bb] * basis[(bb * DIM + k) * DIM + o];
            } else {
                v = root[k * DIM + o];
            }
            WcatT[n * DIM + k] = __float2bfloat16(v);
        } else if (idx < n_cat + n_sq) {
            int t = idx - n_cat; int k = t & 127, o = t >> 7;
            wrelT[o * DIM + k] = __float2bfloat16(w_rel[k * DIM + o]);
        } else if (idx < n_cat + 2 * n_sq) {
            int t = idx - n_cat - n_sq; int k = t & 127, o = t >> 7;
            wrootT[o * DIM + k] = __float2bfloat16(w_root[k * DIM + o]);
        }
    } else if (b < PREP_BLKS + CONV_BLKS) {
        int i = (b - PREP_BLKS) * 256 + threadIdx.x;
        int n4 = N_NODES * DIM / 4;
        if (i < n4) {
            float4 f = x4[i];
            ushort4 o;
            o.x = f2bu(f.x); o.y = f2bu(f.y); o.z = f2bu(f.z); o.w = f2bu(f.w);
            xb4[i] = o;
        }
    } else {
        int e = (b - PREP_BLKS - CONV_BLKS) * 256 + threadIdx.x;
        if (e < N_EDGES) atomicAdd(&deg[ei[N_EDGES + e]], 1);
    }
}

// ---------------- single-pass scan: decoupled lookback (196 blocks, all co-resident) ----------------
// bstate[b] = (1<<32) | block_aggregate, published with device-scope release.
__global__ __launch_bounds__(256) void scan_one(const int* __restrict__ deg, int* __restrict__ segoff,
                                                unsigned long long* __restrict__ bstate, int n) {
    __shared__ int buf[256];
    int b = blockIdx.x, tid = threadIdx.x;
    int i = b * 256 + tid;
    int v = (i < n) ? deg[i] : 0;
    buf[tid] = v;
    __syncthreads();
#pragma unroll
    for (int o = 1; o < 256; o <<= 1) {
        int t = (tid >= o) ? buf[tid - o] : 0;
        __syncthreads();
        buf[tid] += t;
        __syncthreads();
    }
    int incl = buf[tid];
    int total = buf[255];
    if (tid == 0)
        __hip_atomic_store(&bstate[b], (1ULL << 32) | (unsigned)total,
                           __ATOMIC_RELEASE, __HIP_MEMORY_SCOPE_AGENT);
    // lookback: sum aggregates of all predecessor blocks (they publish independently)
    int mysum = 0;
    for (int j = tid; j < b; j += 256) {
        unsigned long long s;
        do {
            s = __hip_atomic_load(&bstate[j], __ATOMIC_ACQUIRE, __HIP_MEMORY_SCOPE_AGENT);
        } while (!(s >> 32));
        mysum += (int)(s & 0xFFFFFFFFu);
    }
    __syncthreads();          // buf free for reduction
    buf[tid] = mysum;
    __syncthreads();
#pragma unroll
    for (int o = 128; o > 0; o >>= 1) {
        if (tid < o) buf[tid] += buf[tid + o];
        __syncthreads();
    }
    int base = buf[0];
    if (i < n) segoff[i + 1] = base + incl;
    if (b == 0 && tid == 0) segoff[0] = 0;
}

// ---------------- FUSED: gemm1 row-panel tiles | sort pass A (place), role by block range ----------------
// gemm (blocks 0..781): proj[M,1152] = xb @ WcatT^T; A-panel staged once, 18 B-tiles, direct
// fragment stores (R10 config — write-path floor). place (blocks 782..1172): coarse-bucket edge
// placement with run-reservation (low write amplification). Independent inputs; saving = launch.
__global__ __launch_bounds__(256) void gemm1_place(const bf16* __restrict__ A, const bf16* __restrict__ BT,
                                                   bf16* __restrict__ C, int M,
                                                   const int* __restrict__ ei, const int* __restrict__ et,
                                                   const float* __restrict__ en, const int* __restrict__ segoff,
                                                   int* __restrict__ bcur, uint2* __restrict__ tmp) {
    __shared__ ushort smem[2 * 64 * 136];    // 34816 B, unioned across roles
    int blk = blockIdx.x;
    if (blk < GEMM1_TILES) {
        ushort (*As)[136] = (ushort(*)[136])smem;
        ushort (*Bs)[136] = (ushort(*)[136])(smem + 64 * 136);
        const ushort* Au = (const ushort*)A;
        const ushort* Bu = (const ushort*)BT;
        ushort* Cu = (ushort*)C;
        int tm = blk * 64;
        int wave = threadIdx.x >> 6, lane = threadIdx.x & 63;
        int q = lane >> 4, mr = lane & 15;

#pragma unroll
        for (int u = 0; u < 4; ++u) {
            int cc = threadIdx.x + u * 256;
            int row = cc >> 4, seg = cc & 15;
            int gr = tm + row;
            short8 av = {0, 0, 0, 0, 0, 0, 0, 0};
            if (gr < M) av = *(const short8*)(Au + (size_t)gr * 128 + seg * 8);
            *(short8*)(&As[row][seg * 8]) = av;
        }

        floatx4 zero = {0.f, 0.f, 0.f, 0.f};
        for (int t = 0; t < 18; ++t) {
            if (t) __syncthreads();
#pragma unroll
            for (int u = 0; u < 4; ++u) {
                int cc = threadIdx.x + u * 256;
                int row = cc >> 4, seg = cc & 15;
                short8 bv = *(const short8*)(Bu + (size_t)(t * 64 + row) * 128 + seg * 8);
                *(short8*)(&Bs[row][seg * 8]) = bv;
            }
            __syncthreads();
            floatx4 acc[4] = {zero, zero, zero, zero};
#pragma unroll
            for (int kt = 0; kt < 4; ++kt) {
                short8 a = *(const short8*)(&As[wave * 16 + mr][q * 8 + kt * 32]);
#pragma unroll
                for (int nt = 0; nt < 4; ++nt) {
                    short8 bb = *(const short8*)(&Bs[nt * 16 + mr][q * 8 + kt * 32]);
                    acc[nt] = __builtin_amdgcn_mfma_f32_16x16x32_bf16(a, bb, acc[nt], 0, 0, 0);
                }
            }
#pragma unroll
            for (int nt = 0; nt < 4; ++nt)
#pragma unroll
                for (int r4 = 0; r4 < 4; ++r4) {
                    int row = tm + wave * 16 + q * 4 + r4;
                    if (row < M) Cu[(size_t)row * NCAT + t * 64 + nt * 16 + mr] = f2bu(acc[nt][r4]);
                }
        }
    } else {
        int* lhist = (int*)smem;
        int* lbase = lhist + NB_C;
        int* lrank = lbase + NB_C;
        int tid = threadIdx.x;
        for (int i = tid; i < NB_C; i += 256) { lhist[i] = 0; lrank[i] = 0; }
        __syncthreads();
        int e0 = (blk - GEMM1_TILES) * EPB_PLACE;
#pragma unroll
        for (int i = 0; i < EPB_PLACE / 256; ++i) {
            int e = e0 + i * 256 + tid;
            if (e < N_EDGES) atomicAdd(&lhist[ei[N_EDGES + e] >> 8], 1);
        }
        __syncthreads();
        for (int c = tid; c < NB_C; c += 256)
            if (lhist[c] > 0) lbase[c] = atomicAdd(&bcur[c], lhist[c]);
        __syncthreads();
#pragma unroll
        for (int i = 0; i < EPB_PLACE / 256; ++i) {
            int e = e0 + i * 256 + tid;
            if (e < N_EDGES) {
                int d = ei[N_EDGES + e];
                int c = d >> 8;
                int r = atomicAdd(&lrank[c], 1);
                int p = segoff[c << 8] + lbase[c] + r;
                tmp[p] = make_uint2((unsigned)ei[e] | ((unsigned)et[e] << 16) | ((unsigned)(d & 255) << 19),
                                    __float_as_uint(en[e]));
            }
        }
    }
}

// ---------------- sort pass B: finalize order within each coarse bucket (all writes block-local) ----------------
__global__ __launch_bounds__(256) void sortb_kernel(const uint2* __restrict__ tmp, const int* __restrict__ segoff,
                                                    uint2* __restrict__ rec) {
    __shared__ int cur[256];
    int c = blockIdx.x;               // 0..195
    int tid = threadIdx.x;
    cur[tid] = 0;
    __syncthreads();
    int base = segoff[c << 8];
    int nlimit = (c + 1) << 8; if (nlimit > N_NODES) nlimit = N_NODES;
    int end = segoff[nlimit];
    for (int i = base + tid; i < end; i += 256) {
        uint2 r = tmp[i];
        int dl = (r.x >> 19) & 255;
        int p = segoff[(c << 8) + dl] + atomicAdd(&cur[dl], 1);
        rec[p] = make_uint2(r.x & 0x7FFFFu, r.y);   // keep src(16) + type(3)
    }
}

// ---------------- layer-1 gather: quarter-wave (16 lanes/node, 16 B/lane), ILP-4 ----------------
__global__ void seg1_kernel(const uint2* __restrict__ rec, const int* __restrict__ segoff,
                            const ushort* __restrict__ proj, const float* __restrict__ bias1,
                            ushort* __restrict__ h) {
    int quad = threadIdx.x >> 4;
    int node = blockIdx.x * 16 + quad;
    if (node >= N_NODES) return;
    int lane = threadIdx.x & 15;
    int s = segoff[node], e = segoff[node + 1];
    float acc[8] = {0.f, 0.f, 0.f, 0.f, 0.f, 0.f, 0.f, 0.f};
    for (int chunk = s; chunk < e; chunk += 4) {
        int m = e - chunk; if (m > 4) m = 4;
        uint2 rr[4]; short8 vv[4];
#pragma unroll
        for (int j = 0; j < 4; ++j) if (j < m) rr[j] = rec[chunk + j];
#pragma unroll
        for (int j = 0; j < 4; ++j) if (j < m) {
            unsigned src = rr[j].x & 0xFFFFu;
            unsigned typ = rr[j].x >> 16;
            vv[j] = *(const short8*)(proj + ((size_t)src * NSLOT + typ) * 128 + lane * 8);
        }
#pragma unroll
        for (int j = 0; j < 4; ++j) if (j < m) {
            float norm = __uint_as_float(rr[j].y);
#pragma unroll
            for (int f = 0; f < 8; ++f) acc[f] += norm * bu2f((ushort)vv[j][f]);
        }
    }
    short8 base = *(const short8*)(proj + ((size_t)node * NSLOT + 8) * 128 + lane * 8);
    short8 o;
#pragma unroll
    for (int f = 0; f < 8; ++f)
        o[f] = (short)f2bu(acc[f] + bu2f((ushort)base[f]) + bias1[lane * 8 + f]);
    *(short8*)(h + (size_t)node * 128 + lane * 8) = o;
}

// ---------------- layer-2 segment sum: quarter-wave, ILP-4 ----------------
__global__ void seg2_kernel(const uint2* __restrict__ rec, const int* __restrict__ segoff,
                            const ushort* __restrict__ h, ushort* __restrict__ out2) {
    int quad = threadIdx.x >> 4;
    int node = blockIdx.x * 16 + quad;
    if (node >= N_NODES) return;
    int lane = threadIdx.x & 15;
    int s = segoff[node], e = segoff[node + 1];
    float acc[8] = {0.f, 0.f, 0.f, 0.f, 0.f, 0.f, 0.f, 0.f};
    for (int chunk = s; chunk < e; chunk += 4) {
        int m = e - chunk; if (m > 4) m = 4;
        uint2 rr[4]; short8 vv[4];
#pragma unroll
        for (int j = 0; j < 4; ++j) if (j < m) rr[j] = rec[chunk + j];
#pragma unroll
        for (int j = 0; j < 4; ++j) if (j < m)
            vv[j] = *(const short8*)(h + (size_t)(rr[j].x & 0xFFFFu) * 128 + lane * 8);
#pragma unroll
        for (int j = 0; j < 4; ++j) if (j < m)
#pragma unroll
            for (int f = 0; f < 8; ++f) acc[f] += bu2f((ushort)vv[j][f]);
    }
    short8 o;
#pragma unroll
    for (int f = 0; f < 8; ++f) o[f] = (short)f2bu(acc[f]);
    *(short8*)(out2 + (size_t)node * 128 + lane * 8) = o;
}

// ---------------- final GEMM: out[M,128](f32) = agg2nd@w_rel + h@w_root + b_rel ----------------
__global__ __launch_bounds__(256) void gemm2_kernel(const bf16* __restrict__ A1, const bf16* __restrict__ B1T,
                                                    const bf16* __restrict__ A2, const bf16* __restrict__ B2T,
                                                    const float* __restrict__ brel, float* __restrict__ out, int M) {
    __shared__ ushort As[64][136];
    __shared__ ushort Bs[64][136];
    int tm = blockIdx.x * 64, tn = blockIdx.y * 64;
    int wave = threadIdx.x >> 6, lane = threadIdx.x & 63;
    int q = lane >> 4, mr = lane & 15;
    floatx4 zero = {0.f, 0.f, 0.f, 0.f};
    floatx4 acc[4] = {zero, zero, zero, zero};

    for (int phase = 0; phase < 2; ++phase) {
        const ushort* Au = (const ushort*)(phase ? A2 : A1);
        const ushort* Bu = (const ushort*)(phase ? B2T : B1T);
        if (phase) __syncthreads();
        for (int c = threadIdx.x; c < 64 * 16; c += 256) {
            int row = c >> 4, seg = c & 15;
            int gr = tm + row;
            short8 av = {0, 0, 0, 0, 0, 0, 0, 0};
            if (gr < M) av = *(const short8*)(Au + (size_t)gr * 128 + seg * 8);
            *(short8*)(&As[row][seg * 8]) = av;
            short8 bv = *(const short8*)(Bu + (size_t)(tn + row) * 128 + seg * 8);
            *(short8*)(&Bs[row][seg * 8]) = bv;
        }
        __syncthreads();
#pragma unroll
        for (int kt = 0; kt < 4; ++kt) {
            short8 a = *(const short8*)(&As[wave * 16 + mr][q * 8 + kt * 32]);
#pragma unroll
            for (int nt = 0; nt < 4; ++nt) {
                short8 b = *(const short8*)(&Bs[nt * 16 + mr][q * 8 + kt * 32]);
                acc[nt] = __builtin_amdgcn_mfma_f32_16x16x32_bf16(a, b, acc[nt], 0, 0, 0);
            }
        }
    }
    __syncthreads();
    float* Csf = (float*)&As[0][0];
#pragma unroll
    for (int nt = 0; nt < 4; ++nt)
#pragma unroll
        for (int r4 = 0; r4 < 4; ++r4) {
            int row = wave * 16 + q * 4 + r4;
            int col = nt * 16 + mr;
            Csf[row * 68 + col] = acc[nt][r4] + brel[tn + col];
        }
    __syncthreads();
#pragma unroll
    for (int u = 0; u < 4; ++u) {
        int cc = threadIdx.x + u * 256;
        int row = cc >> 4, seg = cc & 15;
        int gr = tm + row;
        if (gr < M) {
            float4 v = *(const float4*)(&Csf[row * 68 + seg * 4]);
            *(float4*)(out + (size_t)gr * 128 + tn + seg * 4) = v;
        }
    }
}

extern "C" void kernel_launch(void* const* d_in, const int* in_sizes, int n_in,
                              void* d_out, int out_size, void* d_ws, size_t ws_size,
                              hipStream_t stream) {
    const float* x      = (const float*)d_in[0];
    const int*   ei     = (const int*)d_in[1];
    const int*   et     = (const int*)d_in[2];
    const float* en     = (const float*)d_in[3];
    const float* basis  = (const float*)d_in[4];
    const float* comp   = (const float*)d_in[5];
    const float* root   = (const float*)d_in[6];
    const float* bias1  = (const float*)d_in[7];
    const float* w_rel  = (const float*)d_in[8];
    const float* b_rel  = (const float*)d_in[9];
    const float* w_root = (const float*)d_in[10];
    float* out = (float*)d_out;

    char* ws = (char*)d_ws;
    size_t off = 0;
    auto alloc = [&](size_t bytes) { size_t o = off; off += (bytes + 255) & ~(size_t)255; return o; };

    size_t o_deg    = alloc((size_t)N_NODES * 4);        // zeroed
    size_t o_bcur   = alloc((size_t)NB_C * 4);           // zeroed
    size_t o_bstate = alloc((size_t)SCAN_NB * 8);        // zeroed (contiguous with deg)
    size_t o_segoff = alloc((size_t)(N_NODES + 1) * 4);
    size_t o_rec    = alloc((size_t)N_EDGES * 8);
    size_t o_tmp    = alloc((size_t)N_EDGES * 8);
    size_t o_wcat   = alloc((size_t)NCAT * DIM * 2);
    size_t o_wrel   = alloc((size_t)DIM * DIM * 2);
    size_t o_wroot  = alloc((size_t)DIM * DIM * 2);
    size_t o_xb     = alloc((size_t)N_NODES * DIM * 2);
    size_t o_proj   = alloc((size_t)N_NODES * NCAT * 2); // 115.2 MB
    size_t o_hb     = alloc((size_t)N_NODES * DIM * 2);
    size_t o_agg2   = alloc((size_t)N_NODES * DIM * 2);

    int*   deg    = (int*)(ws + o_deg);
    int*   bcur   = (int*)(ws + o_bcur);
    unsigned long long* bstate = (unsigned long long*)(ws + o_bstate);
    int*   segoff = (int*)(ws + o_segoff);
    uint2* rec    = (uint2*)(ws + o_rec);
    uint2* tmp    = (uint2*)(ws + o_tmp);
    bf16*  wcat   = (bf16*)(ws + o_wcat);
    bf16*  wrelT  = (bf16*)(ws + o_wrel);
    bf16*  wrootT = (bf16*)(ws + o_wroot);
    bf16*  xb     = (bf16*)(ws + o_xb);
    bf16*  proj   = (bf16*)(ws + o_proj);
    bf16*  hb     = (bf16*)(ws + o_hb);
    bf16*  agg2   = (bf16*)(ws + o_agg2);

    // zero deg + bcur + bstate (contiguous padded region)
    hipMemsetAsync(ws + o_deg, 0, o_segoff - o_deg, stream);

    // merged setup: weights prep | x->bf16 | dst histogram
    setup_kernel<<<PREP_BLKS + CONV_BLKS + HIST_BLKS, 256, 0, stream>>>(
        basis, comp, root, w_rel, w_root, wcat, wrelT, wrootT,
        (const float4*)x, (ushort4*)xb, ei, deg);
    // single-pass decoupled-lookback scan
    scan_one<<<SCAN_NB, 256, 0, stream>>>(deg, segoff, bstate, N_NODES);
    // fused: proj GEMM | sort pass A
    gemm1_place<<<GEMM1_TILES + NBLK_PLACE, 256, 0, stream>>>(xb, wcat, proj, N_NODES,
                                                              ei, et, en, segoff, bcur, tmp);
    // sort pass B
    sortb_kernel<<<NB_C, 256, 0, stream>>>(tmp, segoff, rec);
    // layer-1 gather -> h
    seg1_kernel<<<(N_NODES + 15) / 16, 256, 0, stream>>>(rec, segoff, (const ushort*)proj, bias1, (ushort*)hb);
    // layer-2 aggregation
    seg2_kernel<<<(N_NODES + 15) / 16, 256, 0, stream>>>(rec, segoff, (const ushort*)hb, (ushort*)agg2);
    // out = agg2 @ w_rel + h @ w_root + b_rel
    {
        dim3 grid((N_NODES + 63) / 64, DIM / 64);
        gemm2_kernel<<<grid, 256, 0, stream>>>(agg2, wrelT, hb, wrootT, b_rel, out, N_NODES);
    }
}